// Round 5
// baseline (645.134 us; speedup 1.0000x reference)
//
#include <hip/hip_runtime.h>

#define G    128          // 4*HID
#define HID  32
#define EMB  16
#define BB   256
#define TT   2048
#define VOC  5000

typedef float v2f __attribute__((ext_vector_type(2)));
typedef __attribute__((ext_vector_type(8))) short short8;   // 8 bf16 (4 VGPRs)
typedef __attribute__((ext_vector_type(4))) float f32x4;    // MFMA C/D frag

__device__ __forceinline__ float bf2f(unsigned short u) {
    return __uint_as_float(((unsigned)u) << 16);
}
__device__ __forceinline__ unsigned short f2bf(float f) {
    unsigned x = __float_as_uint(f);
    return (unsigned short)((x + 0x7FFFu + ((x >> 16) & 1u)) >> 16);  // RNE
}
__device__ __forceinline__ float sigm(float x) {
    const float e = __expf(-x);
    return __builtin_amdgcn_rcpf(1.f + e);
}
__device__ __forceinline__ float tanh_f(float x) {
    const float e = __expf(-2.f * x);
    return (1.f - e) * __builtin_amdgcn_rcpf(1.f + e);
}
__device__ __forceinline__ float rdlf(float v, int k) {
    return __int_as_float(__builtin_amdgcn_readlane(__float_as_int(v), k));
}

// ---------------------------------------------------------------------------
// Dtype detector (flag=1 -> fp32 buffers, flag=0 -> bf16 buffers). R3-proven.
// ---------------------------------------------------------------------------
__global__ void detect_kernel(const unsigned int* __restrict__ bias_w,
                              int* __restrict__ flag) {
    if (threadIdx.x == 0 && blockIdx.x == 0) {
        bool evens_zero = true, anybig = false;
        for (int i = 0; i < 64; ++i) {
            const unsigned u  = bias_w[i];
            const unsigned lo = u & 0xFFFFu, hi = u >> 16;
            const float vlo = __uint_as_float(lo << 16);
            const float vhi = __uint_as_float(hi & 0xFFFFu ? (hi << 16) : (hi << 16));
            if (lo != 0u) evens_zero = false;
            if (!(fabsf(vlo) < 1e6f) || !(fabsf(__uint_as_float(u & 0xFFFF0000u)) < 1e6f)) anybig = true;
            (void)vhi;
        }
        *flag = (evens_zero || anybig) ? 1 : 0;
    }
}

// ---------------------------------------------------------------------------
// Token z-table: ZK[v][2l] = (i|f col l), ZK[v][2l+1] = (g|o col l+64). R3.
// ---------------------------------------------------------------------------
__global__ __launch_bounds__(64) void zk_kernel(
    const void* __restrict__ emb, const void* __restrict__ Wk,
    const void* __restrict__ bias, float* __restrict__ ZK,
    const int* __restrict__ flag)
{
    const int l = threadIdx.x;
    const int v = blockIdx.x;
    const bool f32 = flag[0] != 0;

    float x[EMB], wa[EMB], wb[EMB], ba, bb;
    if (f32) {
        const float* E = (const float*)emb + (size_t)v * EMB;
        const float* W = (const float*)Wk;
        const float* B = (const float*)bias;
#pragma unroll
        for (int e = 0; e < EMB; ++e) {
            x[e]  = E[e];
            wa[e] = W[e * G + l];
            wb[e] = W[e * G + l + 64];
        }
        ba = B[l]; bb = B[l + 64];
    } else {
        const unsigned short* E = (const unsigned short*)emb + (size_t)v * EMB;
        const unsigned short* W = (const unsigned short*)Wk;
        const unsigned short* B = (const unsigned short*)bias;
#pragma unroll
        for (int e = 0; e < EMB; ++e) {
            x[e]  = bf2f(E[e]);
            wa[e] = bf2f(W[e * G + l]);
            wb[e] = bf2f(W[e * G + l + 64]);
        }
        ba = bf2f(B[l]); bb = bf2f(B[l + 64]);
    }
    float za = ba, zb = bb;
#pragma unroll
    for (int e = 0; e < EMB; ++e) {
        za = fmaf(x[e], wa[e], za);
        zb = fmaf(x[e], wb[e], zb);
    }
    ZK[(size_t)v * G + 2 * l]     = za;
    ZK[(size_t)v * G + 2 * l + 1] = zb;
}

// ---------------------------------------------------------------------------
// Fast scan (R3 skeleton, MFMA matvec): one wave per sequence.
// z = h@Wr done by 8x v_mfma_f32_16x16x32_bf16 against preloaded B-fragments.
// A-fragment (h broadcast to 16 rows) built per step: pair-pack h to bf16,
// 4x ds_bpermute. D extraction: lane j's z_j sits in D#(j>>4) (col=lane&15).
// ---------------------------------------------------------------------------
template <bool F32OUT>
__device__ __forceinline__ void scan_zk_loop(
    const int* __restrict__ trow, const float* __restrict__ ZK,
    void* __restrict__ orow, const short8 (&Bf)[8], int lane)
{
    const bool  lo  = lane < HID;
    const float zsc = lo ? 2.f : 1.f, gm = lo ? 2.f : 1.f, ga = lo ? -1.f : 0.f;
    const int   oj  = lane & (HID - 1);
    const int   g4  = (lane >> 4) & 3;          // which MFMA holds my column
    const bool  odd = lane & 1;
    // bpermute byte-addresses for my 4 A-frag dwords: pair index (lane>>4)*4+q
    int badr[4];
#pragma unroll
    for (int q = 0; q < 4; ++q) badr[q] = 8 * ((lane >> 4) * 4 + q);

    const f32x4 zc = {0.f, 0.f, 0.f, 0.f};
    float h = 0.f, c = 0.f;

    int tcur[16], tnxt[16];
#pragma unroll
    for (int p = 0; p < 16; ++p) tcur[p] = trow[p];
#pragma unroll
    for (int p = 0; p < 16; ++p) tnxt[p] = trow[16 + p];

    v2f pz[4];
#pragma unroll
    for (int d = 0; d < 4; ++d)
        pz[d] = *(const v2f*)(ZK + (size_t)tcur[d] * G + 2 * lane);

    for (int cc = 0; cc < TT / 16; ++cc) {
        const int base = cc * 16;
#pragma unroll
        for (int u = 0; u < 16; ++u) {
            const int t = base + u;
            const v2f z = pz[u & 3];
            {   // prefetch z for t+4
                const int ptok = (u + 4 < 16) ? tcur[u + 4] : tnxt[u + 4 - 16];
                pz[u & 3] = *(const v2f*)(ZK + (size_t)ptok * G + 2 * lane);
            }

            // ---- build A fragment: bf16(h) pairs broadcast to my k-octet ----
            const float hp = __shfl_xor(h, 1);
            const unsigned sr = __float_as_uint(h)  + 0x8000u;   // round-half-up
            const unsigned pr = __float_as_uint(hp) + 0x8000u;
            const unsigned plo = odd ? pr : sr;                  // even-k half
            const unsigned phi = odd ? sr : pr;                  // odd-k half
            const unsigned pair = __builtin_amdgcn_perm(phi, plo, 0x07060302u);
            union { unsigned u4[4]; short8 s8; } au;
#pragma unroll
            for (int q = 0; q < 4; ++q)
                au.u4[q] = (unsigned)__builtin_amdgcn_ds_bpermute(badr[q], (int)pair);
            const short8 Af = au.s8;

            // ---- 8 MFMAs: z columns 0..127 ----
            f32x4 d0 = __builtin_amdgcn_mfma_f32_16x16x32_bf16(Af, Bf[0], zc, 0, 0, 0);
            f32x4 d1 = __builtin_amdgcn_mfma_f32_16x16x32_bf16(Af, Bf[1], zc, 0, 0, 0);
            f32x4 d2 = __builtin_amdgcn_mfma_f32_16x16x32_bf16(Af, Bf[2], zc, 0, 0, 0);
            f32x4 d3 = __builtin_amdgcn_mfma_f32_16x16x32_bf16(Af, Bf[3], zc, 0, 0, 0);
            f32x4 d4 = __builtin_amdgcn_mfma_f32_16x16x32_bf16(Af, Bf[4], zc, 0, 0, 0);
            f32x4 d5 = __builtin_amdgcn_mfma_f32_16x16x32_bf16(Af, Bf[5], zc, 0, 0, 0);
            f32x4 d6 = __builtin_amdgcn_mfma_f32_16x16x32_bf16(Af, Bf[6], zc, 0, 0, 0);
            f32x4 d7 = __builtin_amdgcn_mfma_f32_16x16x32_bf16(Af, Bf[7], zc, 0, 0, 0);

            // my two columns: j = lane (from d[g4]) and j+64 (from d[4+g4])
            const float mva = (g4 < 2) ? (g4 == 0 ? d0.x : d1.x)
                                       : (g4 == 2 ? d2.x : d3.x);
            const float mvb = (g4 < 2) ? (g4 == 0 ? d4.x : d5.x)
                                       : (g4 == 2 ? d6.x : d7.x);
            const float za = z.x + mva;
            const float zb = z.y + mvb;

            const float aa1 = sigm(za);                 // i (lo) | f (hi)
            const float s2  = sigm(zb * zsc);
            const float aa2 = fmaf(s2, gm, ga);         // g (lo) | o (hi)
            const float x1  = __shfl_xor(aa1, 32);
            const float x2  = __shfl_xor(aa2, 32);
            const float iV = lo ? aa1 : x1, fV = lo ? x1 : aa1;
            const float gV = lo ? aa2 : x2, oV = lo ? x2 : aa2;
            const float cN = fmaf(fV, c, iV * gV);
            const float hN = oV * tanh_f(cN);
            const bool  m  = tcur[u] != 0;
            c = m ? cN : c;
            h = m ? hN : h;

            const int oi = t * HID + oj;     // both halves: same addr+data
            if (F32OUT) __builtin_nontemporal_store(h, (float*)orow + oi);
            else        __builtin_nontemporal_store(f2bf(h), (unsigned short*)orow + oi);
        }
        // rotate token chunks, prefetch chunk cc+2
#pragma unroll
        for (int p = 0; p < 16; ++p) tcur[p] = tnxt[p];
        const int nb = (cc + 2) * 16;
        if (nb <= TT - 16) {
#pragma unroll
            for (int p = 0; p < 16; ++p) tnxt[p] = trow[nb + p];
        }
    }
}

__global__ __launch_bounds__(64) void scan_zk_kernel(
    const int* __restrict__ tokens, const float* __restrict__ ZK,
    const void* __restrict__ Wr, const void* __restrict__ bias,
    void* __restrict__ out, const int* __restrict__ flag)
{
    const int lane = threadIdx.x, b = blockIdx.x;
    const bool f32 = flag[0] != 0;

    // B-fragments: MFMA#p covers z-columns 16p..16p+15.
    // Lane holds B[k=(lane>>4)*8+j][n=lane&15], elem j; dword q = (k0+2q, k0+2q+1).
    short8 Bf[8];
    const int n  = lane & 15;
    const int k0 = (lane >> 4) * 8;
#pragma unroll
    for (int p = 0; p < 8; ++p) {
        const int col = 16 * p + n;
        short el[8];
        if (f32) {
            const float* W = (const float*)Wr;
#pragma unroll
            for (int j = 0; j < 8; ++j) el[j] = (short)f2bf(W[(k0 + j) * G + col]);
        } else {
            const unsigned short* W = (const unsigned short*)Wr;
#pragma unroll
            for (int j = 0; j < 8; ++j) el[j] = (short)W[(k0 + j) * G + col];
        }
        short8 s;
#pragma unroll
        for (int j = 0; j < 8; ++j) s[j] = el[j];
        Bf[p] = s;
    }

    const int* trow = tokens + (size_t)b * TT;
    if (f32) scan_zk_loop<true >(trow, ZK, (char*)out + (size_t)b * TT * HID * 4, Bf, lane);
    else     scan_zk_loop<false>(trow, ZK, (char*)out + (size_t)b * TT * HID * 2, Bf, lane);
}

// ---------------------------------------------------------------------------
// Fallback (workspace too small): proven R2/R3 fused kernel.
// ---------------------------------------------------------------------------
template <bool F32>
__device__ __forceinline__ void row_load(const void* emb, int tok, uint4* r) {
    if (F32) { const uint4* p = (const uint4*)((const float*)emb + (size_t)tok*EMB);
               r[0]=p[0]; r[1]=p[1]; r[2]=p[2]; r[3]=p[3]; }
    else     { const uint4* p = (const uint4*)((const unsigned short*)emb + (size_t)tok*EMB);
               r[0]=p[0]; r[1]=p[1]; }
}
template <bool F32>
__device__ __forceinline__ void row_unpack(const uint4* r, float* x) {
    if (F32) {
        const unsigned w[16] = {r[0].x,r[0].y,r[0].z,r[0].w, r[1].x,r[1].y,r[1].z,r[1].w,
                                r[2].x,r[2].y,r[2].z,r[2].w, r[3].x,r[3].y,r[3].z,r[3].w};
#pragma unroll
        for (int e = 0; e < 16; ++e) x[e] = __uint_as_float(w[e]);
    } else {
        const unsigned w[8] = {r[0].x,r[0].y,r[0].z,r[0].w, r[1].x,r[1].y,r[1].z,r[1].w};
#pragma unroll
        for (int q = 0; q < 8; ++q) {
            x[2*q]   = __uint_as_float(w[q] << 16);
            x[2*q+1] = __uint_as_float(w[q] & 0xFFFF0000u);
        }
    }
}

template <bool F32>
__device__ __forceinline__ void scan_fused_loop(
    const int* __restrict__ trow, const void* __restrict__ emb, void* orow,
    const float (&wka)[EMB], const float (&wkb)[EMB],
    const float (&wra)[HID], const float (&wrb)[HID],
    float za0, float zb0, const int* tl, int lane)
{
    const bool  lo  = lane < HID;
    const float zsc = lo ? 2.f : 1.f, gm = lo ? 2.f : 1.f, ga = lo ? -1.f : 0.f;
    float h = 0.f, c = 0.f;
    uint4 praw[2][4];
    row_load<F32>(emb, trow[0], praw[0]);
    row_load<F32>(emb, trow[1], praw[1]);

    for (int tt = 0; tt < TT; tt += 2) {
#pragma unroll
        for (int u = 0; u < 2; ++u) {
            const int t = tt + u;
            float x[EMB];
            row_unpack<F32>(praw[u], x);
            int tn = t + 2; tn = tn > TT - 1 ? TT - 1 : tn;
            row_load<F32>(emb, tl[tn], praw[u]);
            float za = za0, zb = zb0;
#pragma unroll
            for (int e = 0; e < EMB; ++e) { za = fmaf(x[e], wka[e], za); zb = fmaf(x[e], wkb[e], zb); }
#pragma unroll
            for (int k = 0; k < HID; ++k) {
                const float hk = rdlf(h, k);
                za = fmaf(hk, wra[k], za);
                zb = fmaf(hk, wrb[k], zb);
            }
            const float a1 = sigm(za);
            const float s2 = sigm(zb * zsc);
            const float a2 = fmaf(s2, gm, ga);
            const float x1 = __shfl_xor(a1, 32);
            const float x2 = __shfl_xor(a2, 32);
            const float iV = lo ? a1 : x1, fV = lo ? x1 : a1;
            const float gV = lo ? a2 : x2, oV = lo ? x2 : a2;
            const float cN = fmaf(fV, c, iV * gV);
            const float hN = oV * tanh_f(cN);
            const bool  m  = tl[t] != 0;
            c = m ? cN : c;
            h = m ? hN : h;
            const int oi = t * HID + (lane & (HID - 1));
            if (F32) ((float*)orow)[oi] = h;
            else     ((unsigned short*)orow)[oi] = f2bf(h);
        }
    }
}

__global__ __launch_bounds__(64) void scan_fused_kernel(
    const int* __restrict__ tokens, const void* __restrict__ emb,
    const void* __restrict__ Wk, const void* __restrict__ Wr,
    const void* __restrict__ bias, void* __restrict__ out,
    const int* __restrict__ flag, int defmode)
{
    __shared__ int tl[TT];
    const int lane = threadIdx.x, b = blockIdx.x;
    const bool f32 = flag ? (flag[0] != 0) : (defmode != 0);
    const int* trow = tokens + (size_t)b * TT;
    for (int t = lane; t < TT; t += 64) tl[t] = trow[t];

    float wka[EMB], wkb[EMB], wra[HID], wrb[HID], za0, zb0;
    if (f32) {
        const float* WK = (const float*)Wk; const float* WR = (const float*)Wr;
        const float* B  = (const float*)bias;
#pragma unroll
        for (int e = 0; e < EMB; ++e) { wka[e] = WK[e*G + lane]; wkb[e] = WK[e*G + lane + 64]; }
#pragma unroll
        for (int k = 0; k < HID; ++k) { wra[k] = WR[k*G + lane]; wrb[k] = WR[k*G + lane + 64]; }
        za0 = B[lane]; zb0 = B[lane + 64];
    } else {
        const unsigned short* WK = (const unsigned short*)Wk;
        const unsigned short* WR = (const unsigned short*)Wr;
        const unsigned short* B  = (const unsigned short*)bias;
#pragma unroll
        for (int e = 0; e < EMB; ++e) { wka[e] = bf2f(WK[e*G + lane]); wkb[e] = bf2f(WK[e*G + lane + 64]); }
#pragma unroll
        for (int k = 0; k < HID; ++k) { wra[k] = bf2f(WR[k*G + lane]); wrb[k] = bf2f(WR[k*G + lane + 64]); }
        za0 = bf2f(B[lane]); zb0 = bf2f(B[lane + 64]);
    }
    __syncthreads();

    if (f32) scan_fused_loop<true >(trow, emb, (char*)out + (size_t)b*TT*HID*4,
                                    wka, wkb, wra, wrb, za0, zb0, tl, lane);
    else     scan_fused_loop<false>(trow, emb, (char*)out + (size_t)b*TT*HID*2,
                                    wka, wkb, wra, wrb, za0, zb0, tl, lane);
}

// ---------------------------------------------------------------------------
extern "C" void kernel_launch(void* const* d_in, const int* in_sizes, int n_in,
                              void* d_out, int out_size, void* d_ws, size_t ws_size,
                              hipStream_t stream) {
    const int*  tokens = (const int*)d_in[0];
    const void* emb    = d_in[1];
    const void* Wk     = d_in[2];
    const void* Wr     = d_in[3];
    const void* bias   = d_in[4];

    const size_t zk_off   = 256;
    const size_t zk_bytes = (size_t)VOC * G * sizeof(float);   // 2.56 MB

    if (ws_size >= zk_off + zk_bytes) {
        int*   flag = (int*)d_ws;
        float* ZK   = (float*)((char*)d_ws + zk_off);
        detect_kernel<<<1, 64, 0, stream>>>((const unsigned int*)bias, flag);
        zk_kernel<<<VOC, 64, 0, stream>>>(emb, Wk, bias, ZK, flag);
        scan_zk_kernel<<<BB, 64, 0, stream>>>(tokens, ZK, Wr, bias, d_out, flag);
    } else if (ws_size >= 16) {
        int* flag = (int*)d_ws;
        detect_kernel<<<1, 64, 0, stream>>>((const unsigned int*)bias, flag);
        scan_fused_kernel<<<BB, 64, 0, stream>>>(tokens, emb, Wk, Wr, bias, d_out, flag, 1);
    } else {
        scan_fused_kernel<<<BB, 64, 0, stream>>>(tokens, emb, Wk, Wr, bias, d_out, nullptr, 1);
    }
}

// Round 6
// 533.016 us; speedup vs baseline: 1.2103x; 1.2103x over previous
//
#include <hip/hip_runtime.h>

#define G    128          // 4*HID
#define HID  32
#define EMB  16
#define BB   256
#define TT   2048
#define VOC  5000

typedef float v2f __attribute__((ext_vector_type(2)));
typedef __attribute__((ext_vector_type(8))) short short8;   // 8 bf16 (4 VGPRs)
typedef __attribute__((ext_vector_type(4))) float f32x4;    // MFMA C/D frag

__device__ __forceinline__ float bf2f(unsigned short u) {
    return __uint_as_float(((unsigned)u) << 16);
}
__device__ __forceinline__ unsigned short f2bf(float f) {
    unsigned x = __float_as_uint(f);
    return (unsigned short)((x + 0x7FFFu + ((x >> 16) & 1u)) >> 16);  // RNE
}
__device__ __forceinline__ float sigm(float x) {
    const float e = __expf(-x);
    return __builtin_amdgcn_rcpf(1.f + e);
}
__device__ __forceinline__ float tanh_f(float x) {
    const float e = __expf(-2.f * x);
    return (1.f - e) * __builtin_amdgcn_rcpf(1.f + e);
}
__device__ __forceinline__ float rdlf(float v, int k) {
    return __int_as_float(__builtin_amdgcn_readlane(__float_as_int(v), k));
}
// DPP quad-perm lane exchange (pure VALU, ~2 cyc; no LDS pipe)
template <int CTRL>
__device__ __forceinline__ unsigned dppq_u(unsigned v) {
    return (unsigned)__builtin_amdgcn_update_dpp(0, (int)v, CTRL, 0xF, 0xF, true);
}
template <int CTRL>
__device__ __forceinline__ float dppq_f(float v) {
    return __uint_as_float(dppq_u<CTRL>(__float_as_uint(v)));
}
#define DPP_XOR1 0xB1   // quad_perm [1,0,3,2]
#define DPP_XOR2 0x4E   // quad_perm [2,3,0,1]

// dup-pair gate-column mapping: lane l -> first col ca, second col ca+64
__device__ __host__ __forceinline__ int col_a(int l) {
    return (l >> 1) + 32 * (l & 1);
}

// ---------------------------------------------------------------------------
// Dtype detector (flag=1 -> fp32 buffers, flag=0 -> bf16 buffers). Proven.
// ---------------------------------------------------------------------------
__global__ void detect_kernel(const unsigned int* __restrict__ bias_w,
                              int* __restrict__ flag) {
    if (threadIdx.x == 0 && blockIdx.x == 0) {
        bool evens_zero = true, anybig = false;
        for (int i = 0; i < 64; ++i) {
            const unsigned u  = bias_w[i];
            const unsigned lo = u & 0xFFFFu;
            const float vlo = __uint_as_float(lo << 16);
            const float vhi = __uint_as_float(u & 0xFFFF0000u);
            if (lo != 0u) evens_zero = false;
            if (!(fabsf(vlo) < 1e6f) || !(fabsf(vhi) < 1e6f)) anybig = true;
        }
        *flag = (evens_zero || anybig) ? 1 : 0;
    }
}

// ---------------------------------------------------------------------------
// Token z-table, dup-pair permuted: ZK[v][2l] = z_x[col_a(l)],
// ZK[v][2l+1] = z_x[col_a(l)+64].
// ---------------------------------------------------------------------------
__global__ __launch_bounds__(64) void zk_kernel(
    const void* __restrict__ emb, const void* __restrict__ Wk,
    const void* __restrict__ bias, float* __restrict__ ZK,
    const int* __restrict__ flag)
{
    const int l = threadIdx.x;
    const int v = blockIdx.x;
    const bool f32 = flag[0] != 0;
    const int ca = col_a(l), cb = ca + 64;

    float x[EMB], wa[EMB], wb[EMB], ba, bb;
    if (f32) {
        const float* E = (const float*)emb + (size_t)v * EMB;
        const float* W = (const float*)Wk;
        const float* B = (const float*)bias;
#pragma unroll
        for (int e = 0; e < EMB; ++e) {
            x[e]  = E[e];
            wa[e] = W[e * G + ca];
            wb[e] = W[e * G + cb];
        }
        ba = B[ca]; bb = B[cb];
    } else {
        const unsigned short* E = (const unsigned short*)emb + (size_t)v * EMB;
        const unsigned short* W = (const unsigned short*)Wk;
        const unsigned short* B = (const unsigned short*)bias;
#pragma unroll
        for (int e = 0; e < EMB; ++e) {
            x[e]  = bf2f(E[e]);
            wa[e] = bf2f(W[e * G + ca]);
            wb[e] = bf2f(W[e * G + cb]);
        }
        ba = bf2f(B[ca]); bb = bf2f(B[cb]);
    }
    float za = ba, zb = bb;
#pragma unroll
    for (int e = 0; e < EMB; ++e) {
        za = fmaf(x[e], wa[e], za);
        zb = fmaf(x[e], wb[e], zb);
    }
    ZK[(size_t)v * G + 2 * l]     = za;
    ZK[(size_t)v * G + 2 * l + 1] = zb;
}

// ---------------------------------------------------------------------------
// Scan (dup-pair + MFMA): lane l owns hidden unit j=l>>1, half=l&1.
// Per step: A-frag pack via DPP xor2 + 4x ds_bpermute (ONE DS hop),
// 8x mfma_16x16x32_bf16, gate exchange via DPP xor1. No other DS in chain.
// ---------------------------------------------------------------------------
template <bool F32OUT>
__device__ __forceinline__ void scan_zk_loop(
    const int* __restrict__ trow, const float* __restrict__ ZK,
    void* __restrict__ orow, const short8 (&Bf)[8], int lane)
{
    const bool  h0  = (lane & 1) == 0;          // half 0: (i,g); half 1: (f,o)
    const float zsc = h0 ? 2.f : 1.f, gm = h0 ? 2.f : 1.f, ga = h0 ? -1.f : 0.f;
    const int   oj  = lane >> 1;                // my hidden unit
    const int   g4  = (lane >> 4) & 3;          // which MFMA holds my column
    const bool  u_odd = (lane >> 1) & 1;        // my unit index parity
    // bpermute byte-addr: dword q from srclane 16*(lane>>4) + 4q
    int badr[4];
#pragma unroll
    for (int q = 0; q < 4; ++q) badr[q] = 64 * (lane >> 4) + 16 * q;

    const f32x4 zc = {0.f, 0.f, 0.f, 0.f};
    float h = 0.f, c = 0.f;

    int tcur[16], tnxt[16];
#pragma unroll
    for (int p = 0; p < 16; ++p) tcur[p] = trow[p];
#pragma unroll
    for (int p = 0; p < 16; ++p) tnxt[p] = trow[16 + p];

    v2f pz[4];
#pragma unroll
    for (int d = 0; d < 4; ++d)
        pz[d] = *(const v2f*)(ZK + (size_t)tcur[d] * G + 2 * lane);

    for (int cc = 0; cc < TT / 16; ++cc) {
        const int base = cc * 16;
#pragma unroll
        for (int u = 0; u < 16; ++u) {
            const int t = base + u;
            const v2f z = pz[u & 3];
            {   // prefetch z for t+4
                const int ptok = (u + 4 < 16) ? tcur[u + 4] : tnxt[u + 4 - 16];
                pz[u & 3] = *(const v2f*)(ZK + (size_t)ptok * G + 2 * lane);
            }

            // ---- A-frag: bf16(h) pairs via DPP xor2 (unit partner), then
            //      broadcast to k-octets with ONE ds_bpermute hop ----
            const unsigned rh  = __float_as_uint(h) + 0x8000u;   // round-half-up
            const unsigned prt = dppq_u<DPP_XOR2>(rh);           // partner unit
            const unsigned plo = u_odd ? prt : rh;               // even unit
            const unsigned phi = u_odd ? rh : prt;               // odd unit
            const unsigned pair = __builtin_amdgcn_perm(phi, plo, 0x07060302u);
            union { unsigned u4[4]; short8 s8; } au;
#pragma unroll
            for (int q = 0; q < 4; ++q)
                au.u4[q] = (unsigned)__builtin_amdgcn_ds_bpermute(badr[q], (int)pair);
            const short8 Af = au.s8;

            // ---- 8 MFMAs ----
            f32x4 d0 = __builtin_amdgcn_mfma_f32_16x16x32_bf16(Af, Bf[0], zc, 0, 0, 0);
            f32x4 d1 = __builtin_amdgcn_mfma_f32_16x16x32_bf16(Af, Bf[1], zc, 0, 0, 0);
            f32x4 d2 = __builtin_amdgcn_mfma_f32_16x16x32_bf16(Af, Bf[2], zc, 0, 0, 0);
            f32x4 d3 = __builtin_amdgcn_mfma_f32_16x16x32_bf16(Af, Bf[3], zc, 0, 0, 0);
            f32x4 d4 = __builtin_amdgcn_mfma_f32_16x16x32_bf16(Af, Bf[4], zc, 0, 0, 0);
            f32x4 d5 = __builtin_amdgcn_mfma_f32_16x16x32_bf16(Af, Bf[5], zc, 0, 0, 0);
            f32x4 d6 = __builtin_amdgcn_mfma_f32_16x16x32_bf16(Af, Bf[6], zc, 0, 0, 0);
            f32x4 d7 = __builtin_amdgcn_mfma_f32_16x16x32_bf16(Af, Bf[7], zc, 0, 0, 0);

            // my columns: first gate from d[g4], second from d[4+g4]
            const float mva = (g4 < 2) ? (g4 == 0 ? d0.x : d1.x)
                                       : (g4 == 2 ? d2.x : d3.x);
            const float mvb = (g4 < 2) ? (g4 == 0 ? d4.x : d5.x)
                                       : (g4 == 2 ? d6.x : d7.x);
            const float za = z.x + mva;
            const float zb = z.y + mvb;

            const float aa1 = sigm(za);                 // i (h0) | f (h1)
            const float s2  = sigm(zb * zsc);
            const float aa2 = fmaf(s2, gm, ga);         // g (h0) | o (h1)
            const float x1  = dppq_f<DPP_XOR1>(aa1);    // partner gate (VALU)
            const float x2  = dppq_f<DPP_XOR1>(aa2);
            const float iV = h0 ? aa1 : x1, fV = h0 ? x1 : aa1;
            const float gV = h0 ? aa2 : x2, oV = h0 ? x2 : aa2;
            const float cN = fmaf(fV, c, iV * gV);
            const float hN = oV * tanh_f(cN);
            const bool  m  = tcur[u] != 0;
            c = m ? cN : c;
            h = m ? hN : h;

            const int oi = t * HID + oj;     // pair lanes: same addr+data
            if (F32OUT) __builtin_nontemporal_store(h, (float*)orow + oi);
            else        __builtin_nontemporal_store(f2bf(h), (unsigned short*)orow + oi);
        }
        // rotate token chunks, prefetch chunk cc+2
#pragma unroll
        for (int p = 0; p < 16; ++p) tcur[p] = tnxt[p];
        const int nb = (cc + 2) * 16;
        if (nb <= TT - 16) {
#pragma unroll
            for (int p = 0; p < 16; ++p) tnxt[p] = trow[nb + p];
        }
    }
}

__global__ __launch_bounds__(64) void scan_zk_kernel(
    const int* __restrict__ tokens, const float* __restrict__ ZK,
    const void* __restrict__ Wr, const void* __restrict__ bias,
    void* __restrict__ out, const int* __restrict__ flag)
{
    const int lane = threadIdx.x, b = blockIdx.x;
    const bool f32 = flag[0] != 0;

    // B-frags: MFMA q<4 -> first-gate cols ca(16q+n); q>=4 -> cb(16(q-4)+n).
    // Lane holds B[k=(lane>>4)*8+j][n=lane&15].
    short8 Bf[8];
    const int n  = lane & 15;
    const int k0 = (lane >> 4) * 8;
#pragma unroll
    for (int p = 0; p < 8; ++p) {
        const int ell = 16 * (p & 3) + n;
        const int col = (p < 4) ? col_a(ell) : (col_a(ell) + 64);
        short el[8];
        if (f32) {
            const float* W = (const float*)Wr;
#pragma unroll
            for (int j = 0; j < 8; ++j) el[j] = (short)f2bf(W[(k0 + j) * G + col]);
        } else {
            const unsigned short* W = (const unsigned short*)Wr;
#pragma unroll
            for (int j = 0; j < 8; ++j) el[j] = (short)W[(k0 + j) * G + col];
        }
        short8 s;
#pragma unroll
        for (int j = 0; j < 8; ++j) s[j] = el[j];
        Bf[p] = s;
    }

    const int* trow = tokens + (size_t)b * TT;
    if (f32) scan_zk_loop<true >(trow, ZK, (char*)out + (size_t)b * TT * HID * 4, Bf, lane);
    else     scan_zk_loop<false>(trow, ZK, (char*)out + (size_t)b * TT * HID * 2, Bf, lane);
}

// ---------------------------------------------------------------------------
// Fallback (workspace too small): proven R2/R3 fused kernel.
// ---------------------------------------------------------------------------
template <bool F32>
__device__ __forceinline__ void row_load(const void* emb, int tok, uint4* r) {
    if (F32) { const uint4* p = (const uint4*)((const float*)emb + (size_t)tok*EMB);
               r[0]=p[0]; r[1]=p[1]; r[2]=p[2]; r[3]=p[3]; }
    else     { const uint4* p = (const uint4*)((const unsigned short*)emb + (size_t)tok*EMB);
               r[0]=p[0]; r[1]=p[1]; }
}
template <bool F32>
__device__ __forceinline__ void row_unpack(const uint4* r, float* x) {
    if (F32) {
        const unsigned w[16] = {r[0].x,r[0].y,r[0].z,r[0].w, r[1].x,r[1].y,r[1].z,r[1].w,
                                r[2].x,r[2].y,r[2].z,r[2].w, r[3].x,r[3].y,r[3].z,r[3].w};
#pragma unroll
        for (int e = 0; e < 16; ++e) x[e] = __uint_as_float(w[e]);
    } else {
        const unsigned w[8] = {r[0].x,r[0].y,r[0].z,r[0].w, r[1].x,r[1].y,r[1].z,r[1].w};
#pragma unroll
        for (int q = 0; q < 8; ++q) {
            x[2*q]   = __uint_as_float(w[q] << 16);
            x[2*q+1] = __uint_as_float(w[q] & 0xFFFF0000u);
        }
    }
}

template <bool F32>
__device__ __forceinline__ void scan_fused_loop(
    const int* __restrict__ trow, const void* __restrict__ emb, void* orow,
    const float (&wka)[EMB], const float (&wkb)[EMB],
    const float (&wra)[HID], const float (&wrb)[HID],
    float za0, float zb0, const int* tl, int lane)
{
    const bool  lo  = lane < HID;
    const float zsc = lo ? 2.f : 1.f, gm = lo ? 2.f : 1.f, ga = lo ? -1.f : 0.f;
    float h = 0.f, c = 0.f;
    uint4 praw[2][4];
    row_load<F32>(emb, trow[0], praw[0]);
    row_load<F32>(emb, trow[1], praw[1]);

    for (int tt = 0; tt < TT; tt += 2) {
#pragma unroll
        for (int u = 0; u < 2; ++u) {
            const int t = tt + u;
            float x[EMB];
            row_unpack<F32>(praw[u], x);
            int tn = t + 2; tn = tn > TT - 1 ? TT - 1 : tn;
            row_load<F32>(emb, tl[tn], praw[u]);
            float za = za0, zb = zb0;
#pragma unroll
            for (int e = 0; e < EMB; ++e) { za = fmaf(x[e], wka[e], za); zb = fmaf(x[e], wkb[e], zb); }
#pragma unroll
            for (int k = 0; k < HID; ++k) {
                const float hk = rdlf(h, k);
                za = fmaf(hk, wra[k], za);
                zb = fmaf(hk, wrb[k], zb);
            }
            const float a1 = sigm(za);
            const float s2 = sigm(zb * zsc);
            const float a2 = fmaf(s2, gm, ga);
            const float x1 = __shfl_xor(a1, 32);
            const float x2 = __shfl_xor(a2, 32);
            const float iV = lo ? a1 : x1, fV = lo ? x1 : a1;
            const float gV = lo ? a2 : x2, oV = lo ? x2 : a2;
            const float cN = fmaf(fV, c, iV * gV);
            const float hN = oV * tanh_f(cN);
            const bool  m  = tl[t] != 0;
            c = m ? cN : c;
            h = m ? hN : h;
            const int oi = t * HID + (lane & (HID - 1));
            if (F32) ((float*)orow)[oi] = h;
            else     ((unsigned short*)orow)[oi] = f2bf(h);
        }
    }
}

__global__ __launch_bounds__(64) void scan_fused_kernel(
    const int* __restrict__ tokens, const void* __restrict__ emb,
    const void* __restrict__ Wk, const void* __restrict__ Wr,
    const void* __restrict__ bias, void* __restrict__ out,
    const int* __restrict__ flag, int defmode)
{
    __shared__ int tl[TT];
    const int lane = threadIdx.x, b = blockIdx.x;
    const bool f32 = flag ? (flag[0] != 0) : (defmode != 0);
    const int* trow = tokens + (size_t)b * TT;
    for (int t = lane; t < TT; t += 64) tl[t] = trow[t];

    float wka[EMB], wkb[EMB], wra[HID], wrb[HID], za0, zb0;
    if (f32) {
        const float* WK = (const float*)Wk; const float* WR = (const float*)Wr;
        const float* B  = (const float*)bias;
#pragma unroll
        for (int e = 0; e < EMB; ++e) { wka[e] = WK[e*G + lane]; wkb[e] = WK[e*G + lane + 64]; }
#pragma unroll
        for (int k = 0; k < HID; ++k) { wra[k] = WR[k*G + lane]; wrb[k] = WR[k*G + lane + 64]; }
        za0 = B[lane]; zb0 = B[lane + 64];
    } else {
        const unsigned short* WK = (const unsigned short*)Wk;
        const unsigned short* WR = (const unsigned short*)Wr;
        const unsigned short* B  = (const unsigned short*)bias;
#pragma unroll
        for (int e = 0; e < EMB; ++e) { wka[e] = bf2f(WK[e*G + lane]); wkb[e] = bf2f(WK[e*G + lane + 64]); }
#pragma unroll
        for (int k = 0; k < HID; ++k) { wra[k] = bf2f(WR[k*G + lane]); wrb[k] = bf2f(WR[k*G + lane + 64]); }
        za0 = bf2f(B[lane]); zb0 = bf2f(B[lane + 64]);
    }
    __syncthreads();

    if (f32) scan_fused_loop<true >(trow, emb, (char*)out + (size_t)b*TT*HID*4,
                                    wka, wkb, wra, wrb, za0, zb0, tl, lane);
    else     scan_fused_loop<false>(trow, emb, (char*)out + (size_t)b*TT*HID*2,
                                    wka, wkb, wra, wrb, za0, zb0, tl, lane);
}

// ---------------------------------------------------------------------------
extern "C" void kernel_launch(void* const* d_in, const int* in_sizes, int n_in,
                              void* d_out, int out_size, void* d_ws, size_t ws_size,
                              hipStream_t stream) {
    const int*  tokens = (const int*)d_in[0];
    const void* emb    = d_in[1];
    const void* Wk     = d_in[2];
    const void* Wr     = d_in[3];
    const void* bias   = d_in[4];

    const size_t zk_off   = 256;
    const size_t zk_bytes = (size_t)VOC * G * sizeof(float);   // 2.56 MB

    if (ws_size >= zk_off + zk_bytes) {
        int*   flag = (int*)d_ws;
        float* ZK   = (float*)((char*)d_ws + zk_off);
        detect_kernel<<<1, 64, 0, stream>>>((const unsigned int*)bias, flag);
        zk_kernel<<<VOC, 64, 0, stream>>>(emb, Wk, bias, ZK, flag);
        scan_zk_kernel<<<BB, 64, 0, stream>>>(tokens, ZK, Wr, bias, d_out, flag);
    } else if (ws_size >= 16) {
        int* flag = (int*)d_ws;
        detect_kernel<<<1, 64, 0, stream>>>((const unsigned int*)bias, flag);
        scan_fused_kernel<<<BB, 64, 0, stream>>>(tokens, emb, Wk, Wr, bias, d_out, flag, 1);
    } else {
        scan_fused_kernel<<<BB, 64, 0, stream>>>(tokens, emb, Wk, Wr, bias, d_out, nullptr, 1);
    }
}